// Round 6
// baseline (877.070 us; speedup 1.0000x reference)
//
#include <hip/hip_runtime.h>
#include <stdint.h>

// VQ-VAE nearest-codeword quantization, MI355X (gfx950).
// M=16384 rows, D=256 dims, K=8192 codewords.
// argmin_k ||x-c_k||^2 == argmin_k ( ||c_k||^2 - 2 x.c_k )
//
// R13: R8 structure restored (R12's launch_bounds(256,4) forced VGPR 84->64
// and spilled: WRITE_SIZE 94MB; reverted to (256,3), proven VGPR=84 clean).
// ONE structural change to vq_main, per the m201/T4 counted-vmcnt template:
//  - 3 LDS buffers (48KB), DMA issued TWO stages ahead (prologue stages 0,1).
//  - per-stage sync is `s_waitcnt vmcnt(4)` + raw s_barrier (not
//    __syncthreads): each wave waits only for its 4 oldest loads (the stage
//    it is about to read); the next stage's 4 stay in flight ACROSS the
//    barrier. Kills the implicit vmcnt(0) drain R8 paid 8x per block.
//  - 8 stages fully unrolled so all %3 buffer indices are compile-time.
// Race safety: DMA(c+2) overwrites buf((c-1)%3); its last readers finished
// before barrier(c) which orders them; "memory" clobber on the waitcnt asm
// pins ds_reads below the wait. In-order vmem returns make vmcnt(4) ==
// "DMA(c) landed" (the 4 newest outstanding are DMA(c+1)'s).
// merge: reverted to the serial-rescore version (R0 residue 107.8 vs R1
// parallel 114.0; serial loads only the actual nq qualifiers, nq ~ 2-3).
// Unchanged, proven: 16-chunk XOR swizzle (0 conflicts), Ap=-2x with c2 in
// the MFMA C operand, med3 sorted top-4, forced-RTNE fp8, TOP-4 per 512-col
// split, EPS=20 fp64 rescore, ties -> smaller index like np.argmin.

#define M_ROWS 16384
#define D_DIM  256
#define K_CB   8192
#define NSPLIT 16           // 512 codewords per split
#define CHUNK  64           // cols staged per barrier
#define EPS 20.0f

typedef float f32x4 __attribute__((ext_vector_type(4)));
typedef int   int4v __attribute__((ext_vector_type(4)));
typedef int   int8v __attribute__((ext_vector_type(8)));

__device__ __forceinline__ uint32_t umin32(uint32_t a, uint32_t b) { return a < b ? a : b; }
__device__ __forceinline__ uint32_t umax32(uint32_t a, uint32_t b) { return a > b ? a : b; }

// packed values are positive normal floats: float compare == uint compare
__device__ __forceinline__ uint32_t fmin32(uint32_t a, uint32_t b) {
  return __float_as_uint(fminf(__uint_as_float(a), __uint_as_float(b)));
}
__device__ __forceinline__ uint32_t fmed32(uint32_t a, uint32_t b, uint32_t c) {
  return __float_as_uint(__builtin_amdgcn_fmed3f(
      __uint_as_float(a), __uint_as_float(b), __uint_as_float(c)));
}

__device__ __forceinline__ void gld_lds16(const void* g, void* l) {
  // async global->LDS, 16B/lane; LDS dest is wave-uniform base + lane*16.
  __builtin_amdgcn_global_load_lds((__attribute__((address_space(1))) void*)g,
                                   (__attribute__((address_space(3))) void*)l,
                                   16, 0, 0);
}

// round f32 to 3 mantissa bits, RTNE (carry into exponent handled by the add)
__device__ __forceinline__ float rtne3(float f) {
  uint32_t u = __float_as_uint(f);
  u = (u + 0x0007FFFFu + ((u >> 20) & 1u)) & 0xFFF00000u;
  return __uint_as_float(u);
}

__device__ __forceinline__ uint32_t fp8x4(const f32x4 v) {
  // pre-rounded values are exactly representable -> intrinsic is exact
  int p = __builtin_amdgcn_cvt_pk_fp8_f32(rtne3(v[0]), rtne3(v[1]), 0, false);
  p = __builtin_amdgcn_cvt_pk_fp8_f32(rtne3(v[2]), rtne3(v[3]), p, true);
  return (uint32_t)p;
}

// -- prep: x -> Ap fp8(-2x) + out_ze ; cb -> Bp fp8 + c2s = ||c||^2+1024 ----
__global__ __launch_bounds__(256) void prep(const float* __restrict__ x,
                                            const float* __restrict__ cb,
                                            uint8_t* __restrict__ Ap,
                                            uint8_t* __restrict__ Bp,
                                            float* __restrict__ c2s,
                                            float* __restrict__ out_ze) {
  const int w = threadIdx.x >> 6, lane = threadIdx.x & 63;
  if (blockIdx.x < M_ROWS / 4) {
    const int row = blockIdx.x * 4 + w;                 // one wave per x row
    const f32x4 v = *(const f32x4*)(x + (size_t)row * D_DIM + lane * 4);
    // store -2x: exact (sign+exponent), q(-2x)q(c) == -2 q(x)q(c) bit-exact,
    // so the EPS error bound is unchanged. |2x| <= ~11 << 448 (e4m3 max).
    f32x4 nv;
#pragma unroll
    for (int t = 0; t < 4; ++t) nv[t] = -2.0f * v[t];
    *(uint32_t*)(Ap + (size_t)row * D_DIM + lane * 4) = fp8x4(nv);
    *(f32x4*)(out_ze + (size_t)row * D_DIM + lane * 4) = v;   // identity encoder
  } else {
    const int row = (blockIdx.x - M_ROWS / 4) * 4 + w;  // one wave per codeword
    const f32x4 v = *(const f32x4*)(cb + (size_t)row * D_DIM + lane * 4);
    *(uint32_t*)(Bp + (size_t)row * D_DIM + lane * 4) = fp8x4(v);
    double s = 0.0;
#pragma unroll
    for (int t = 0; t < 4; ++t) s += (double)v[t] * (double)v[t];
#pragma unroll
    for (int m = 1; m < 64; m <<= 1) s += __shfl_xor(s, m, 64);
    if (lane == 0) c2s[row] = (float)s + 1024.0f;       // pre-shifted: s>0 packing
  }
}

// ---- main: fp8 K=256 GEMM, 3-buf counted-vmcnt DMA pipeline, fused top-4 ----
__global__ __launch_bounds__(256, 3) void vq_main(const uint8_t* __restrict__ Ap,
                                                  const uint8_t* __restrict__ Bp,
                                                  const float* __restrict__ c2s,
                                                  uint4* __restrict__ part) {
  __shared__ uint8_t Bs[3][CHUNK * D_DIM];   // 3 x 16 KB, chunk-swizzled

  const int w    = threadIdx.x >> 6;
  const int lane = threadIdx.x & 63;
  const int fr   = lane & 15;         // frag m/n index
  const int fq   = lane >> 4;         // frag k-quarter (32 contiguous bytes)

  const int rowBase = blockIdx.x * 128 + w * 32;        // wave owns 32 rows
  const int colBase = blockIdx.y * 512;                 // block owns one split

  // A fragments (-2x) for the whole kernel
  int8v af[2][2];
  {
    const uint8_t* ab = Ap + (size_t)(rowBase + fr) * D_DIM + fq * 32;
#pragma unroll
    for (int i = 0; i < 2; ++i)
#pragma unroll
      for (int kh = 0; kh < 2; ++kh)
        af[i][kh] = *(const int8v*)(ab + (size_t)(i * 16) * D_DIM + kh * 128);
  }

  // stage-invariant DMA offsets: row rr = ii*4+dRow within the wave's 16 rows;
  // phys 16B chunk p of row n holds logical chunk p^(n&15), applied on the
  // GLOBAL source address (gld dest is wave-uniform base + lane*16).
  const int dRow = lane >> 4;
  const int dChk = lane & 15;
  int goff[4];
#pragma unroll
  for (int ii = 0; ii < 4; ++ii) {
    const int rr = ii * 4 + dRow;                       // == row & 15
    goff[ii] = rr * D_DIM + ((dChk ^ rr) << 4);
  }

#define STAGE_DMA(c, buf)                                                      \
  {                                                                            \
    const uint8_t* gb = Bp + ((size_t)(colBase + (c) * CHUNK + w * 16) << 8);  \
    uint8_t* lb = &Bs[buf][w * 16 * D_DIM] + lane * 16;                        \
    _Pragma("unroll")                                                          \
    for (int ii = 0; ii < 4; ++ii)                                             \
      gld_lds16(gb + goff[ii], lb + ii * 4 * D_DIM);                           \
  }

  // sorted top-4 per slot [i][r], packed ((s+1024) bits & ~511) | col9
  uint32_t t1[2][4], t2[2][4], t3[2][4], t4[2][4];
#pragma unroll
  for (int i = 0; i < 2; ++i)
#pragma unroll
    for (int r = 0; r < 4; ++r) {
      t1[i][r] = 0x7f7ffe00u; t2[i][r] = 0x7f7ffe00u;
      t3[i][r] = 0x7f7ffe00u; t4[i][r] = 0x7f7ffe00u;
    }

  const float* c2p = c2s + colBase + fr;
  const int y0 = (fq * 2) << 4;                         // logical 32B k-quarter

  STAGE_DMA(0, 0);                  // 2-deep prologue: stages 0 and 1 in flight
  STAGE_DMA(1, 1);

#pragma unroll
  for (int c = 0; c < 512 / CHUNK; ++c) {               // 8 stages, full unroll
    // counted wait: per-wave 4 loads/stage; <=4 outstanding leaves DMA(c+1)
    // flying across the barrier while guaranteeing DMA(c) has landed
    // (vmem returns are in-order). "memory" pins ds_reads below the wait.
    if (c < 512 / CHUNK - 1) {
      asm volatile("s_waitcnt vmcnt(4)" ::: "memory");
    } else {
      asm volatile("s_waitcnt vmcnt(0)" ::: "memory");
    }
    __builtin_amdgcn_s_barrier();
    if (c + 2 < 512 / CHUNK) STAGE_DMA(c + 2, (c + 2) % 3);

    const uint8_t* bsb = Bs[c % 3];
    const int cb0 = c * CHUNK;
    float cvv[4];
#pragma unroll
    for (int jj = 0; jj < 4; ++jj)                      // hoist c2 loads
      cvv[jj] = c2p[cb0 + jj * 16];

#pragma unroll
    for (int jj = 0; jj < 4; ++jj) {                    // 4 col-frags of 16
      const uint8_t* bp = bsb + (jj * 16 + fr) * D_DIM;
      const float cv = cvv[jj];
      f32x4 acc[2];
      acc[0] = (f32x4){cv, cv, cv, cv};                 // c2 pre-loaded into C
      acc[1] = (f32x4){cv, cv, cv, cv};
#pragma unroll
      for (int kh = 0; kh < 2; ++kh) {
        const int y = (y0 ^ (fr << 4)) ^ (kh << 7);     // ((L0^fr)<<4)
        const int4v lo = *(const int4v*)(bp + y);
        const int4v hi = *(const int4v*)(bp + (y ^ 16));
        int8v bf;
#pragma unroll
        for (int t = 0; t < 4; ++t) { bf[t] = lo[t]; bf[4 + t] = hi[t]; }
#pragma unroll
        for (int i = 0; i < 2; ++i)
          acc[i] = __builtin_amdgcn_mfma_scale_f32_16x16x128_f8f6f4(
              af[i][kh], bf, acc[i], 0, 0,       // cbsz=fp8, blgp=fp8
              0, 0x7f7f7f7f, 0, 0x7f7f7f7f);     // unit E8M0 scales
      }
      // epilogue: acc == s = (1024+c2) - 2*cross; pack; med3 top-4 insert
      const int col9 = cb0 + jj * 16 + fr;
#pragma unroll
      for (int i = 0; i < 2; ++i)
#pragma unroll
        for (int r = 0; r < 4; ++r) {
          const uint32_t p =
              (__float_as_uint(acc[i][r]) & ~511u) | (uint32_t)col9;
          const uint32_t o1 = t1[i][r], o2 = t2[i][r];
          const uint32_t o3 = t3[i][r], o4 = t4[i][r];
          t1[i][r] = fmin32(p, o1);                 // 4 independent ops,
          t2[i][r] = fmed32(p, o1, o2);             // no serial chain
          t3[i][r] = fmed32(p, o2, o3);
          t4[i][r] = fmed32(p, o3, o4);
        }
    }
  }

  // cross-fr bitonic merge (lanes with same fq hold the same rows, disjoint
  // cols); lane fr==0 of each fq then stores its rows' top-4 directly.
#pragma unroll
  for (int i = 0; i < 2; ++i)
#pragma unroll
    for (int r = 0; r < 4; ++r) {
      uint32_t a1 = t1[i][r], a2 = t2[i][r], a3 = t3[i][r], a4 = t4[i][r];
#pragma unroll
      for (int m = 1; m < 16; m <<= 1) {
        const uint32_t b1 = __shfl_xor(a1, m, 64);
        const uint32_t b2 = __shfl_xor(a2, m, 64);
        const uint32_t b3 = __shfl_xor(a3, m, 64);
        const uint32_t b4 = __shfl_xor(a4, m, 64);
        uint32_t c1 = umin32(a1, b4), c2_ = umin32(a2, b3);
        uint32_t c3 = umin32(a3, b2), c4 = umin32(a4, b1);
        uint32_t lo, hi;
        lo = umin32(c1, c3); hi = umax32(c1, c3); c1 = lo; c3 = hi;
        lo = umin32(c2_, c4); hi = umax32(c2_, c4); c2_ = lo; c4 = hi;
        lo = umin32(c1, c2_); hi = umax32(c1, c2_); c1 = lo; c2_ = hi;
        lo = umin32(c3, c4); hi = umax32(c3, c4); c3 = lo; c4 = hi;
        a1 = c1; a2 = c2_; a3 = c3; a4 = c4;
      }
      if (fr == 0) {
        const int row = rowBase + i * 16 + fq * 4 + r;   // C/D layout (m89)
        part[(size_t)row * NSPLIT + blockIdx.y] = make_uint4(a1, a2, a3, a4);
      }
    }
}

// -------- merge: 64 candidates/row -> certain winner or fp64 rescore --------
__global__ __launch_bounds__(256) void vq_merge(const uint32_t* __restrict__ part,
                                                const float* __restrict__ x,
                                                const float* __restrict__ cb,
                                                float* __restrict__ out) {
  const int w = threadIdx.x >> 6, lane = threadIdx.x & 63;
  const int row = blockIdx.x * 4 + w;                 // one wave per row

  const uint32_t pk = part[(size_t)row * 64 + lane];  // coalesced, 1 cand/lane
  const int gidx = (lane >> 2) * (K_CB / NSPLIT) + (int)(pk & 511u);

  // integer min == numeric min (all packed values positive)
  uint32_t pmin = pk;
#pragma unroll
  for (int m = 1; m < 64; m <<= 1) {
    const uint32_t o = __shfl_xor(pmin, m, 64);
    pmin = pmin < o ? pmin : o;
  }
  const float vmin = __uint_as_float(pmin & ~511u);
  const float vme  = __uint_as_float(pk & ~511u);
  const unsigned long long mask = __ballot(vme <= vmin + EPS);

  int winner;
  if (__popcll(mask) == 1) {
    winner = __shfl(gidx, __ffsll((long long)mask) - 1, 64);
  } else {
    // exact fp64 rescore of the qualifiers (ties -> smaller index, like np)
    const f32x4 xv = *(const f32x4*)(x + (size_t)row * D_DIM + lane * 4);
    double bestd = 1.0e300;
    int bidx = 0x7fffffff;
    unsigned long long mm = mask;
    while (mm) {
      const int q = __ffsll((long long)mm) - 1;
      mm &= mm - 1;
      const int ci = __shfl(gidx, q, 64);
      const f32x4 cv = *(const f32x4*)(cb + (size_t)ci * D_DIM + lane * 4);
      double s = 0.0;
#pragma unroll
      for (int t = 0; t < 4; ++t) {
        const double dx = (double)xv[t] - (double)cv[t];
        s += dx * dx;
      }
#pragma unroll
      for (int m = 1; m < 64; m <<= 1) s += __shfl_xor(s, m, 64);
      if (s < bestd || (s == bestd && ci < bidx)) { bestd = s; bidx = ci; }
    }
    winner = bidx;
  }

  float* out_recon = out;                               // out_ze written by prep
  float* out_zq    = out + 2 * (size_t)M_ROWS * D_DIM;
  float* out_idx   = out + 3 * (size_t)M_ROWS * D_DIM;

  const f32x4 cv = *(const f32x4*)(cb + (size_t)winner * D_DIM + lane * 4);
  *(f32x4*)(out_recon + (size_t)row * D_DIM + lane * 4) = cv;  // identity decoder
  *(f32x4*)(out_zq    + (size_t)row * D_DIM + lane * 4) = cv;
  if (lane == 0) out_idx[row] = (float)winner;
}

extern "C" void kernel_launch(void* const* d_in, const int* in_sizes, int n_in,
                              void* d_out, int out_size, void* d_ws, size_t ws_size,
                              hipStream_t stream) {
  const float* x  = (const float*)d_in[0];
  const float* cb = (const float*)d_in[1];
  float* out = (float*)d_out;

  // ws: c2s 32 KB | part uint4[16384][16] 4 MB | Ap fp8 4 MB | Bp fp8 2 MB | pad
  char* ws = (char*)d_ws;
  float*    c2s  = (float*)ws;
  uint4*    part = (uint4*)(ws + 32768);
  uint8_t*  Ap   = (uint8_t*)(ws + 32768 + 4194304);
  uint8_t*  Bp   = Ap + (size_t)M_ROWS * D_DIM;
  if (ws_size < (size_t)(32768 + 4194304 + 4194304 + 2097152 + 4096)) return;

  float* out_ze = out + (size_t)M_ROWS * D_DIM;

  prep    <<<dim3(M_ROWS / 4 + K_CB / 4), dim3(256), 0, stream>>>(x, cb, Ap, Bp, c2s, out_ze);
  vq_main <<<dim3(M_ROWS / 128, NSPLIT), dim3(256), 0, stream>>>(Ap, Bp, c2s, part);
  vq_merge<<<dim3(M_ROWS / 4), dim3(256), 0, stream>>>((const uint32_t*)part, x, cb, out);
}

// Round 7
// 175.318 us; speedup vs baseline: 5.0028x; 5.0028x over previous
//
#include <hip/hip_runtime.h>
#include <stdint.h>

// VQ-VAE nearest-codeword quantization, MI355X (gfx950).
// M=16384 rows, D=256 dims, K=8192 codewords.
// argmin_k ||x-c_k||^2 == argmin_k ( ||c_k||^2 - 2 x.c_k )
//
// R14: REVERT to the proven-best composition after R13's counted-vmcnt graft
// thrashed HBM (FETCH 995MB/WRITE 1.4GB, 780us -- naive sync-structure graft
// onto a 2-barrier loop, exactly the documented T4-without-8-phase failure).
//  - vq_main: byte-identical to R8 (65.4us proven: VGPR 84, WRITE 4MB,
//    0 bank conflicts, MfmaUtil 21/VALUBusy 60). 2 LDS buffers, __syncthreads
//    per 64-col stage, DMA issued a full stage ahead of its consuming
//    barrier, 16-chunk XOR swizzle.
//  - merge: serial-rescore version (R0 residue 107.8us vs R1 parallel 114.0:
//    serial fetches only the actual nq~2-3 qualifiers).
// Refuted levers (counter evidence): no-LDS register streaming (R9-R11,
// latency-bound 136-223us; hipcc collapses reg pipelines), launch_bounds
// (256,4) (R12, forced spill), counted vmcnt+raw barrier (R13, HBM thrash).
// Numerics, proven absmax 0.0: forced-RTNE fp8, Ap=-2x with c2 pre-loaded
// in the MFMA C operand, med3 sorted top-4 per 512-col split, EPS=20 fp64
// rescore, ties -> smaller index like np.argmin.

#define M_ROWS 16384
#define D_DIM  256
#define K_CB   8192
#define NSPLIT 16           // 512 codewords per split
#define CHUNK  64           // cols staged per barrier
#define EPS 20.0f

typedef float f32x4 __attribute__((ext_vector_type(4)));
typedef int   int4v __attribute__((ext_vector_type(4)));
typedef int   int8v __attribute__((ext_vector_type(8)));

__device__ __forceinline__ uint32_t umin32(uint32_t a, uint32_t b) { return a < b ? a : b; }
__device__ __forceinline__ uint32_t umax32(uint32_t a, uint32_t b) { return a > b ? a : b; }

// packed values are positive normal floats: float compare == uint compare
__device__ __forceinline__ uint32_t fmin32(uint32_t a, uint32_t b) {
  return __float_as_uint(fminf(__uint_as_float(a), __uint_as_float(b)));
}
__device__ __forceinline__ uint32_t fmed32(uint32_t a, uint32_t b, uint32_t c) {
  return __float_as_uint(__builtin_amdgcn_fmed3f(
      __uint_as_float(a), __uint_as_float(b), __uint_as_float(c)));
}

__device__ __forceinline__ void gld_lds16(const void* g, void* l) {
  // async global->LDS, 16B/lane; LDS dest is wave-uniform base + lane*16.
  __builtin_amdgcn_global_load_lds((__attribute__((address_space(1))) void*)g,
                                   (__attribute__((address_space(3))) void*)l,
                                   16, 0, 0);
}

// round f32 to 3 mantissa bits, RTNE (carry into exponent handled by the add)
__device__ __forceinline__ float rtne3(float f) {
  uint32_t u = __float_as_uint(f);
  u = (u + 0x0007FFFFu + ((u >> 20) & 1u)) & 0xFFF00000u;
  return __uint_as_float(u);
}

__device__ __forceinline__ uint32_t fp8x4(const f32x4 v) {
  // pre-rounded values are exactly representable -> intrinsic is exact
  int p = __builtin_amdgcn_cvt_pk_fp8_f32(rtne3(v[0]), rtne3(v[1]), 0, false);
  p = __builtin_amdgcn_cvt_pk_fp8_f32(rtne3(v[2]), rtne3(v[3]), p, true);
  return (uint32_t)p;
}

// -- prep: x -> Ap fp8(-2x) + out_ze ; cb -> Bp fp8 + c2s = ||c||^2+1024 ----
__global__ __launch_bounds__(256) void prep(const float* __restrict__ x,
                                            const float* __restrict__ cb,
                                            uint8_t* __restrict__ Ap,
                                            uint8_t* __restrict__ Bp,
                                            float* __restrict__ c2s,
                                            float* __restrict__ out_ze) {
  const int w = threadIdx.x >> 6, lane = threadIdx.x & 63;
  if (blockIdx.x < M_ROWS / 4) {
    const int row = blockIdx.x * 4 + w;                 // one wave per x row
    const f32x4 v = *(const f32x4*)(x + (size_t)row * D_DIM + lane * 4);
    // store -2x: exact (sign+exponent), q(-2x)q(c) == -2 q(x)q(c) bit-exact,
    // so the EPS error bound is unchanged. |2x| <= ~11 << 448 (e4m3 max).
    f32x4 nv;
#pragma unroll
    for (int t = 0; t < 4; ++t) nv[t] = -2.0f * v[t];
    *(uint32_t*)(Ap + (size_t)row * D_DIM + lane * 4) = fp8x4(nv);
    *(f32x4*)(out_ze + (size_t)row * D_DIM + lane * 4) = v;   // identity encoder
  } else {
    const int row = (blockIdx.x - M_ROWS / 4) * 4 + w;  // one wave per codeword
    const f32x4 v = *(const f32x4*)(cb + (size_t)row * D_DIM + lane * 4);
    *(uint32_t*)(Bp + (size_t)row * D_DIM + lane * 4) = fp8x4(v);
    double s = 0.0;
#pragma unroll
    for (int t = 0; t < 4; ++t) s += (double)v[t] * (double)v[t];
#pragma unroll
    for (int m = 1; m < 64; m <<= 1) s += __shfl_xor(s, m, 64);
    if (lane == 0) c2s[row] = (float)s + 1024.0f;       // pre-shifted: s>0 packing
  }
}

// ---- main: fp8 K=256 GEMM, DMA-pipelined LDS B, fused packed top-4/split ----
__global__ __launch_bounds__(256, 3) void vq_main(const uint8_t* __restrict__ Ap,
                                                  const uint8_t* __restrict__ Bp,
                                                  const float* __restrict__ c2s,
                                                  uint4* __restrict__ part) {
  __shared__ uint8_t Bs[2][CHUNK * D_DIM];   // 2 x 16 KB, chunk-swizzled

  const int w    = threadIdx.x >> 6;
  const int lane = threadIdx.x & 63;
  const int fr   = lane & 15;         // frag m/n index
  const int fq   = lane >> 4;         // frag k-quarter (32 contiguous bytes)

  const int rowBase = blockIdx.x * 128 + w * 32;        // wave owns 32 rows
  const int colBase = blockIdx.y * 512;                 // block owns one split

  // A fragments (-2x) for the whole kernel
  int8v af[2][2];
  {
    const uint8_t* ab = Ap + (size_t)(rowBase + fr) * D_DIM + fq * 32;
#pragma unroll
    for (int i = 0; i < 2; ++i)
#pragma unroll
      for (int kh = 0; kh < 2; ++kh)
        af[i][kh] = *(const int8v*)(ab + (size_t)(i * 16) * D_DIM + kh * 128);
  }

  // stage-invariant DMA offsets: row rr = ii*4+dRow within the wave's 16 rows;
  // phys 16B chunk p of row n holds logical chunk p^(n&15), applied on the
  // GLOBAL source address (gld dest is wave-uniform base + lane*16).
  const int dRow = lane >> 4;
  const int dChk = lane & 15;
  int goff[4];
#pragma unroll
  for (int ii = 0; ii < 4; ++ii) {
    const int rr = ii * 4 + dRow;                       // == row & 15
    goff[ii] = rr * D_DIM + ((dChk ^ rr) << 4);
  }

#define STAGE_DMA(c, buf)                                                      \
  {                                                                            \
    const uint8_t* gb = Bp + ((size_t)(colBase + (c) * CHUNK + w * 16) << 8);  \
    uint8_t* lb = &Bs[buf][w * 16 * D_DIM] + lane * 16;                        \
    _Pragma("unroll")                                                          \
    for (int ii = 0; ii < 4; ++ii)                                             \
      gld_lds16(gb + goff[ii], lb + ii * 4 * D_DIM);                           \
  }

  // sorted top-4 per slot [i][r], packed ((s+1024) bits & ~511) | col9
  uint32_t t1[2][4], t2[2][4], t3[2][4], t4[2][4];
#pragma unroll
  for (int i = 0; i < 2; ++i)
#pragma unroll
    for (int r = 0; r < 4; ++r) {
      t1[i][r] = 0x7f7ffe00u; t2[i][r] = 0x7f7ffe00u;
      t3[i][r] = 0x7f7ffe00u; t4[i][r] = 0x7f7ffe00u;
    }

  const float* c2p = c2s + colBase + fr;
  const int y0 = (fq * 2) << 4;                         // logical 32B k-quarter

  STAGE_DMA(0, 0);

  for (int c = 0; c < 512 / CHUNK; ++c) {               // 8 stages
    __syncthreads();              // DMA[c] landed (issued a full stage ago)
    if (c < 512 / CHUNK - 1) STAGE_DMA(c + 1, (c + 1) & 1);

    const uint8_t* bsb = Bs[c & 1];
    const int cb0 = c * CHUNK;
    float cvv[4];
#pragma unroll
    for (int jj = 0; jj < 4; ++jj)                      // hoist c2 loads
      cvv[jj] = c2p[cb0 + jj * 16];

#pragma unroll
    for (int jj = 0; jj < 4; ++jj) {                    // 4 col-frags of 16
      const uint8_t* bp = bsb + (jj * 16 + fr) * D_DIM;
      const float cv = cvv[jj];
      f32x4 acc[2];
      acc[0] = (f32x4){cv, cv, cv, cv};                 // c2 pre-loaded into C
      acc[1] = (f32x4){cv, cv, cv, cv};
#pragma unroll
      for (int kh = 0; kh < 2; ++kh) {
        const int y = (y0 ^ (fr << 4)) ^ (kh << 7);     // ((L0^fr)<<4)
        const int4v lo = *(const int4v*)(bp + y);
        const int4v hi = *(const int4v*)(bp + (y ^ 16));
        int8v bf;
#pragma unroll
        for (int t = 0; t < 4; ++t) { bf[t] = lo[t]; bf[4 + t] = hi[t]; }
#pragma unroll
        for (int i = 0; i < 2; ++i)
          acc[i] = __builtin_amdgcn_mfma_scale_f32_16x16x128_f8f6f4(
              af[i][kh], bf, acc[i], 0, 0,       // cbsz=fp8, blgp=fp8
              0, 0x7f7f7f7f, 0, 0x7f7f7f7f);     // unit E8M0 scales
      }
      // epilogue: acc == s = (1024+c2) - 2*cross; pack; med3 top-4 insert
      const int col9 = cb0 + jj * 16 + fr;
#pragma unroll
      for (int i = 0; i < 2; ++i)
#pragma unroll
        for (int r = 0; r < 4; ++r) {
          const uint32_t p =
              (__float_as_uint(acc[i][r]) & ~511u) | (uint32_t)col9;
          const uint32_t o1 = t1[i][r], o2 = t2[i][r];
          const uint32_t o3 = t3[i][r], o4 = t4[i][r];
          t1[i][r] = fmin32(p, o1);                 // 4 independent ops,
          t2[i][r] = fmed32(p, o1, o2);             // no serial chain
          t3[i][r] = fmed32(p, o2, o3);
          t4[i][r] = fmed32(p, o3, o4);
        }
    }
  }

  // cross-fr bitonic merge (lanes with same fq hold the same rows, disjoint
  // cols); lane fr==0 of each fq then stores its rows' top-4 directly.
#pragma unroll
  for (int i = 0; i < 2; ++i)
#pragma unroll
    for (int r = 0; r < 4; ++r) {
      uint32_t a1 = t1[i][r], a2 = t2[i][r], a3 = t3[i][r], a4 = t4[i][r];
#pragma unroll
      for (int m = 1; m < 16; m <<= 1) {
        const uint32_t b1 = __shfl_xor(a1, m, 64);
        const uint32_t b2 = __shfl_xor(a2, m, 64);
        const uint32_t b3 = __shfl_xor(a3, m, 64);
        const uint32_t b4 = __shfl_xor(a4, m, 64);
        uint32_t c1 = umin32(a1, b4), c2_ = umin32(a2, b3);
        uint32_t c3 = umin32(a3, b2), c4 = umin32(a4, b1);
        uint32_t lo, hi;
        lo = umin32(c1, c3); hi = umax32(c1, c3); c1 = lo; c3 = hi;
        lo = umin32(c2_, c4); hi = umax32(c2_, c4); c2_ = lo; c4 = hi;
        lo = umin32(c1, c2_); hi = umax32(c1, c2_); c1 = lo; c2_ = hi;
        lo = umin32(c3, c4); hi = umax32(c3, c4); c3 = lo; c4 = hi;
        a1 = c1; a2 = c2_; a3 = c3; a4 = c4;
      }
      if (fr == 0) {
        const int row = rowBase + i * 16 + fq * 4 + r;   // C/D layout (m89)
        part[(size_t)row * NSPLIT + blockIdx.y] = make_uint4(a1, a2, a3, a4);
      }
    }
}

// -------- merge: 64 candidates/row -> certain winner or fp64 rescore --------
__global__ __launch_bounds__(256) void vq_merge(const uint32_t* __restrict__ part,
                                                const float* __restrict__ x,
                                                const float* __restrict__ cb,
                                                float* __restrict__ out) {
  const int w = threadIdx.x >> 6, lane = threadIdx.x & 63;
  const int row = blockIdx.x * 4 + w;                 // one wave per row

  const uint32_t pk = part[(size_t)row * 64 + lane];  // coalesced, 1 cand/lane
  const int gidx = (lane >> 2) * (K_CB / NSPLIT) + (int)(pk & 511u);

  // integer min == numeric min (all packed values positive)
  uint32_t pmin = pk;
#pragma unroll
  for (int m = 1; m < 64; m <<= 1) {
    const uint32_t o = __shfl_xor(pmin, m, 64);
    pmin = pmin < o ? pmin : o;
  }
  const float vmin = __uint_as_float(pmin & ~511u);
  const float vme  = __uint_as_float(pk & ~511u);
  const unsigned long long mask = __ballot(vme <= vmin + EPS);

  int winner;
  if (__popcll(mask) == 1) {
    winner = __shfl(gidx, __ffsll((long long)mask) - 1, 64);
  } else {
    // exact fp64 rescore of the qualifiers (ties -> smaller index, like np)
    const f32x4 xv = *(const f32x4*)(x + (size_t)row * D_DIM + lane * 4);
    double bestd = 1.0e300;
    int bidx = 0x7fffffff;
    unsigned long long mm = mask;
    while (mm) {
      const int q = __ffsll((long long)mm) - 1;
      mm &= mm - 1;
      const int ci = __shfl(gidx, q, 64);
      const f32x4 cv = *(const f32x4*)(cb + (size_t)ci * D_DIM + lane * 4);
      double s = 0.0;
#pragma unroll
      for (int t = 0; t < 4; ++t) {
        const double dx = (double)xv[t] - (double)cv[t];
        s += dx * dx;
      }
#pragma unroll
      for (int m = 1; m < 64; m <<= 1) s += __shfl_xor(s, m, 64);
      if (s < bestd || (s == bestd && ci < bidx)) { bestd = s; bidx = ci; }
    }
    winner = bidx;
  }

  float* out_recon = out;                               // out_ze written by prep
  float* out_zq    = out + 2 * (size_t)M_ROWS * D_DIM;
  float* out_idx   = out + 3 * (size_t)M_ROWS * D_DIM;

  const f32x4 cv = *(const f32x4*)(cb + (size_t)winner * D_DIM + lane * 4);
  *(f32x4*)(out_recon + (size_t)row * D_DIM + lane * 4) = cv;  // identity decoder
  *(f32x4*)(out_zq    + (size_t)row * D_DIM + lane * 4) = cv;
  if (lane == 0) out_idx[row] = (float)winner;
}

extern "C" void kernel_launch(void* const* d_in, const int* in_sizes, int n_in,
                              void* d_out, int out_size, void* d_ws, size_t ws_size,
                              hipStream_t stream) {
  const float* x  = (const float*)d_in[0];
  const float* cb = (const float*)d_in[1];
  float* out = (float*)d_out;

  // ws: c2s 32 KB | part uint4[16384][16] 4 MB | Ap fp8 4 MB | Bp fp8 2 MB | pad
  char* ws = (char*)d_ws;
  float*    c2s  = (float*)ws;
  uint4*    part = (uint4*)(ws + 32768);
  uint8_t*  Ap   = (uint8_t*)(ws + 32768 + 4194304);
  uint8_t*  Bp   = Ap + (size_t)M_ROWS * D_DIM;
  if (ws_size < (size_t)(32768 + 4194304 + 4194304 + 2097152 + 4096)) return;

  float* out_ze = out + (size_t)M_ROWS * D_DIM;

  prep    <<<dim3(M_ROWS / 4 + K_CB / 4), dim3(256), 0, stream>>>(x, cb, Ap, Bp, c2s, out_ze);
  vq_main <<<dim3(M_ROWS / 128, NSPLIT), dim3(256), 0, stream>>>(Ap, Bp, c2s, part);
  vq_merge<<<dim3(M_ROWS / 4), dim3(256), 0, stream>>>((const uint32_t*)part, x, cb, out);
}